// Round 9
// baseline (13221.603 us; speedup 1.0000x reference)
//
#include <hip/hip_runtime.h>
#include <math.h>

#define B_ 32
#define T_ 64
#define S_ 256
#define H_ 1024
#define E_ 512
#define BH_ (B_ * H_)

__device__ __forceinline__ float sigm(float x) {
    return 1.0f / (1.0f + __expf(-x));
}
__device__ __forceinline__ float tanh_(float x) {
    x = fminf(15.0f, fmaxf(-15.0f, x));
    float e = __expf(-2.0f * x);
    return (1.0f - e) / (1.0f + e);
}

// ---------------------------------------------------------------------------
// init: state ping-pong slot 0 + zero input feed
// ---------------------------------------------------------------------------
__global__ void k_init(const float* __restrict__ h0in, const float* __restrict__ c0in,
                       float* h0s, float* c0s, float* h1s, float* c1s, float* feed) {
    int i = blockIdx.x * 256 + threadIdx.x;
    if (i < BH_) {
        h0s[i]  = h0in[i];
        h1s[i]  = h0in[BH_ + i];
        c0s[i]  = c0in[i];
        c1s[i]  = c0in[BH_ + i];
        feed[i] = 0.0f;
    }
}

// ---------------------------------------------------------------------------
// pmem[r][k] = sum_j mem[r][j] * w_in[j][k]   (r = b*S+s; time-invariant)
// grid (128, 16), block 256.  64x64 tile, K-chunk 32, 4x4 outputs/thread.
// ---------------------------------------------------------------------------
__global__ __launch_bounds__(256) void k_pmem(
    const float* __restrict__ mem, const float* __restrict__ w_in,
    float* __restrict__ pmem)
{
    __shared__ float As[64][36];   // [row][k]  +pad
    __shared__ float Bs[32][68];   // [k][col]  +pad

    const int tid = threadIdx.x;
    const int rt = blockIdx.x * 64;
    const int ct = blockIdx.y * 64;
    const int tx = tid & 15;       // col group
    const int ty = tid >> 4;       // row group

    float acc[4][4] = {{0.f}};

    for (int jc = 0; jc < 1024; jc += 32) {
        #pragma unroll
        for (int i = 0; i < 2; ++i) {
            int s2  = tid + i * 256;            // 0..511
            int row = s2 >> 3, kq = s2 & 7;
            *(float4*)&As[row][kq * 4] =
                *(const float4*)(mem + (size_t)(rt + row) * 1024 + jc + kq * 4);
        }
        #pragma unroll
        for (int i = 0; i < 2; ++i) {
            int s2 = tid + i * 256;
            int kk = s2 >> 4, cq = s2 & 15;
            *(float4*)&Bs[kk][cq * 4] =
                *(const float4*)(w_in + (size_t)(jc + kk) * 1024 + ct + cq * 4);
        }
        __syncthreads();

        #pragma unroll
        for (int kk = 0; kk < 32; ++kk) {
            float a0 = As[ty * 4 + 0][kk], a1 = As[ty * 4 + 1][kk];
            float a2 = As[ty * 4 + 2][kk], a3 = As[ty * 4 + 3][kk];
            float b0 = Bs[kk][tx * 4 + 0], b1 = Bs[kk][tx * 4 + 1];
            float b2 = Bs[kk][tx * 4 + 2], b3 = Bs[kk][tx * 4 + 3];
            acc[0][0] += a0 * b0; acc[0][1] += a0 * b1; acc[0][2] += a0 * b2; acc[0][3] += a0 * b3;
            acc[1][0] += a1 * b0; acc[1][1] += a1 * b1; acc[1][2] += a1 * b2; acc[1][3] += a1 * b3;
            acc[2][0] += a2 * b0; acc[2][1] += a2 * b1; acc[2][2] += a2 * b2; acc[2][3] += a2 * b3;
            acc[3][0] += a3 * b0; acc[3][1] += a3 * b1; acc[3][2] += a3 * b2; acc[3][3] += a3 * b3;
        }
        __syncthreads();
    }

    #pragma unroll
    for (int i = 0; i < 4; ++i) {
        float4 v = make_float4(acc[i][0], acc[i][1], acc[i][2], acc[i][3]);
        *(float4*)(pmem + (size_t)(rt + ty * 4 + i) * 1024 + ct + tx * 4) = v;
    }
}

// ===========================================================================
// Software-pipelined GEMM kernels: grid 512, block 256 = 32 b x 2 jl x 4 ks.
// Double-buffered LDS A-tile; next chunk prefetched to registers during the
// current chunk's weight-load+FMA phase; ONE barrier per chunk.
// ===========================================================================

// -------- LSTM layer 0: K = 2560 = [emb 512 | feed 1024 | h0 1024] ---------
__global__ __launch_bounds__(256) void k_lstm0(
    const int* __restrict__ tgt, const float* __restrict__ emb,
    const float* __restrict__ w_ih0, const float* __restrict__ w_hh0,
    const float* __restrict__ b_ih0, const float* __restrict__ b_hh0,
    const float* __restrict__ feed, const float* __restrict__ h0c,
    const float* __restrict__ c0c,
    float* __restrict__ h0n, float* __restrict__ c0n, int t)
{
    __shared__ float As[2][4][32][68];     // 69.6 KB double buffer
    __shared__ float red[3][64][4];
    __shared__ int   tok[32];

    int tid = threadIdx.x;
    int b  = tid & 31;
    int jl = (tid >> 5) & 1;
    int ks = tid >> 6;
    int j  = blockIdx.x * 2 + jl;

    if (tid < 32) tok[tid] = tgt[tid * T_ + t];
    __syncthreads();

    float acc0, acc1, acc2, acc3;
    if (ks == 0) {
        acc0 = b_ih0[0 * H_ + j] + b_hh0[0 * H_ + j];
        acc1 = b_ih0[1 * H_ + j] + b_hh0[1 * H_ + j];
        acc2 = b_ih0[2 * H_ + j] + b_hh0[2 * H_ + j];
        acc3 = b_ih0[3 * H_ + j] + b_hh0[3 * H_ + j];
    } else {
        acc0 = acc1 = acc2 = acc3 = 0.0f;
    }

    // prologue: chunk 0 -> registers
    float4 r[8];
    #pragma unroll
    for (int i = 0; i < 8; ++i) {
        int q   = tid + i * 256;
        int ksq = q >> 9, rem = q & 511, bb = rem >> 4, kq = rem & 15;
        int kg  = ksq * 640 + kq * 4;
        const float* src;
        if (kg < 512)        src = emb  + (size_t)tok[bb] * E_ + kg;
        else if (kg < 1536)  src = feed + (size_t)bb * H_ + (kg - 512);
        else                 src = h0c  + (size_t)bb * H_ + (kg - 1536);
        r[i] = *(const float4*)src;
    }

    for (int c = 0; c < 10; ++c) {
        const int buf = c & 1;
        #pragma unroll
        for (int i = 0; i < 8; ++i) {
            int q   = tid + i * 256;
            int ksq = q >> 9, rem = q & 511, bb = rem >> 4, kq = rem & 15;
            *(float4*)&As[buf][ksq][bb][kq * 4] = r[i];
        }
        __syncthreads();

        if (c < 9) {   // prefetch chunk c+1
            #pragma unroll
            for (int i = 0; i < 8; ++i) {
                int q   = tid + i * 256;
                int ksq = q >> 9, rem = q & 511, bb = rem >> 4, kq = rem & 15;
                int kg  = ksq * 640 + (c + 1) * 64 + kq * 4;
                const float* src;
                if (kg < 512)        src = emb  + (size_t)tok[bb] * E_ + kg;
                else if (kg < 1536)  src = feed + (size_t)bb * H_ + (kg - 512);
                else                 src = h0c  + (size_t)bb * H_ + (kg - 1536);
                r[i] = *(const float4*)src;
            }
        }

        int kbase = ks * 640 + c * 64;
        const float4 *w0, *w1, *w2, *w3;
        if (kbase < 1536) {
            w0 = (const float4*)(w_ih0 + (size_t)(0 * H_ + j) * 1536 + kbase);
            w1 = (const float4*)(w_ih0 + (size_t)(1 * H_ + j) * 1536 + kbase);
            w2 = (const float4*)(w_ih0 + (size_t)(2 * H_ + j) * 1536 + kbase);
            w3 = (const float4*)(w_ih0 + (size_t)(3 * H_ + j) * 1536 + kbase);
        } else {
            int kb = kbase - 1536;
            w0 = (const float4*)(w_hh0 + (size_t)(0 * H_ + j) * 1024 + kb);
            w1 = (const float4*)(w_hh0 + (size_t)(1 * H_ + j) * 1024 + kb);
            w2 = (const float4*)(w_hh0 + (size_t)(2 * H_ + j) * 1024 + kb);
            w3 = (const float4*)(w_hh0 + (size_t)(3 * H_ + j) * 1024 + kb);
        }
        const float4* A4 = (const float4*)&As[buf][ks][b][0];
        #pragma unroll
        for (int kk = 0; kk < 16; ++kk) {
            float4 a  = A4[kk];
            float4 q0 = w0[kk], q1 = w1[kk], q2 = w2[kk], q3 = w3[kk];
            acc0 += a.x * q0.x + a.y * q0.y + a.z * q0.z + a.w * q0.w;
            acc1 += a.x * q1.x + a.y * q1.y + a.z * q1.z + a.w * q1.w;
            acc2 += a.x * q2.x + a.y * q2.y + a.z * q2.z + a.w * q2.w;
            acc3 += a.x * q3.x + a.y * q3.y + a.z * q3.z + a.w * q3.w;
        }
        // no trailing barrier: next iteration writes the OTHER buffer, and its
        // barrier guarantees all waves finished this compute before buffer reuse
    }

    __syncthreads();
    int idx = tid & 63;
    if (ks > 0) {
        red[ks - 1][idx][0] = acc0; red[ks - 1][idx][1] = acc1;
        red[ks - 1][idx][2] = acc2; red[ks - 1][idx][3] = acc3;
    }
    __syncthreads();
    if (ks == 0) {
        #pragma unroll
        for (int r2 = 0; r2 < 3; ++r2) {
            acc0 += red[r2][idx][0]; acc1 += red[r2][idx][1];
            acc2 += red[r2][idx][2]; acc3 += red[r2][idx][3];
        }
        float co = c0c[b * H_ + j];
        float cn = sigm(acc1) * co + sigm(acc0) * tanh_(acc2);
        float hn = sigm(acc3) * tanh_(cn);
        c0n[b * H_ + j] = cn;
        h0n[b * H_ + j] = hn;
    }
}

// -------- LSTM layer 1: K = 2048 = [h0n 1024 | h1 1024] --------------------
__global__ __launch_bounds__(256) void k_lstm1(
    const float* __restrict__ w_ih1, const float* __restrict__ w_hh1,
    const float* __restrict__ b_ih1, const float* __restrict__ b_hh1,
    const float* __restrict__ x, const float* __restrict__ h1c,
    const float* __restrict__ c1c,
    float* __restrict__ h1n, float* __restrict__ c1n)
{
    __shared__ float As[2][4][32][68];
    __shared__ float red[3][64][4];

    int tid = threadIdx.x;
    int b  = tid & 31;
    int jl = (tid >> 5) & 1;
    int ks = tid >> 6;
    int j  = blockIdx.x * 2 + jl;

    float acc0, acc1, acc2, acc3;
    if (ks == 0) {
        acc0 = b_ih1[0 * H_ + j] + b_hh1[0 * H_ + j];
        acc1 = b_ih1[1 * H_ + j] + b_hh1[1 * H_ + j];
        acc2 = b_ih1[2 * H_ + j] + b_hh1[2 * H_ + j];
        acc3 = b_ih1[3 * H_ + j] + b_hh1[3 * H_ + j];
    } else {
        acc0 = acc1 = acc2 = acc3 = 0.0f;
    }

    float4 r[8];
    #pragma unroll
    for (int i = 0; i < 8; ++i) {
        int q   = tid + i * 256;
        int ksq = q >> 9, rem = q & 511, bb = rem >> 4, kq = rem & 15;
        int kg  = ksq * 512 + kq * 4;
        const float* src = (kg < 1024) ? (x + (size_t)bb * H_ + kg)
                                       : (h1c + (size_t)bb * H_ + (kg - 1024));
        r[i] = *(const float4*)src;
    }

    for (int c = 0; c < 8; ++c) {
        const int buf = c & 1;
        #pragma unroll
        for (int i = 0; i < 8; ++i) {
            int q   = tid + i * 256;
            int ksq = q >> 9, rem = q & 511, bb = rem >> 4, kq = rem & 15;
            *(float4*)&As[buf][ksq][bb][kq * 4] = r[i];
        }
        __syncthreads();

        if (c < 7) {
            #pragma unroll
            for (int i = 0; i < 8; ++i) {
                int q   = tid + i * 256;
                int ksq = q >> 9, rem = q & 511, bb = rem >> 4, kq = rem & 15;
                int kg  = ksq * 512 + (c + 1) * 64 + kq * 4;
                const float* src = (kg < 1024) ? (x + (size_t)bb * H_ + kg)
                                               : (h1c + (size_t)bb * H_ + (kg - 1024));
                r[i] = *(const float4*)src;
            }
        }

        int kbase = ks * 512 + c * 64;
        const float* wb;
        int ko;
        if (kbase < 1024) { wb = w_ih1; ko = kbase; }
        else              { wb = w_hh1; ko = kbase - 1024; }
        const float4* w0 = (const float4*)(wb + (size_t)(0 * H_ + j) * H_ + ko);
        const float4* w1 = (const float4*)(wb + (size_t)(1 * H_ + j) * H_ + ko);
        const float4* w2 = (const float4*)(wb + (size_t)(2 * H_ + j) * H_ + ko);
        const float4* w3 = (const float4*)(wb + (size_t)(3 * H_ + j) * H_ + ko);
        const float4* A4 = (const float4*)&As[buf][ks][b][0];
        #pragma unroll
        for (int kk = 0; kk < 16; ++kk) {
            float4 a  = A4[kk];
            float4 q0 = w0[kk], q1 = w1[kk], q2 = w2[kk], q3 = w3[kk];
            acc0 += a.x * q0.x + a.y * q0.y + a.z * q0.z + a.w * q0.w;
            acc1 += a.x * q1.x + a.y * q1.y + a.z * q1.z + a.w * q1.w;
            acc2 += a.x * q2.x + a.y * q2.y + a.z * q2.z + a.w * q2.w;
            acc3 += a.x * q3.x + a.y * q3.y + a.z * q3.z + a.w * q3.w;
        }
    }

    __syncthreads();
    int idx = tid & 63;
    if (ks > 0) {
        red[ks - 1][idx][0] = acc0; red[ks - 1][idx][1] = acc1;
        red[ks - 1][idx][2] = acc2; red[ks - 1][idx][3] = acc3;
    }
    __syncthreads();
    if (ks == 0) {
        #pragma unroll
        for (int r2 = 0; r2 < 3; ++r2) {
            acc0 += red[r2][idx][0]; acc1 += red[r2][idx][1];
            acc2 += red[r2][idx][2]; acc3 += red[r2][idx][3];
        }
        float co = c1c[b * H_ + j];
        float cn = sigm(acc1) * co + sigm(acc0) * tanh_(acc2);
        float hn = sigm(acc3) * tanh_(cn);
        c1n[b * H_ + j] = cn;
        h1n[b * H_ + j] = hn;
    }
}

// -------- q = h1n @ w_in^T (FALLBACK PATH ONLY) ----------------------------
__global__ __launch_bounds__(256) void k_q(
    const float* __restrict__ w_in, const float* __restrict__ h1n,
    float* __restrict__ q_out)
{
    __shared__ float As[4][32][68];
    __shared__ float red[3][64];

    int tid = threadIdx.x;
    int b  = tid & 31;
    int jl = (tid >> 5) & 1;
    int ks = tid >> 6;
    int j  = blockIdx.x * 2 + jl;

    float acc = 0.0f;
    for (int c = 0; c < 4; ++c) {
        #pragma unroll
        for (int i = 0; i < 8; ++i) {
            int q   = tid + i * 256;
            int ksq = q >> 9;
            int rem = q & 511;
            int bb  = rem >> 4;
            int kq  = rem & 15;
            int kg  = ksq * 256 + c * 64 + kq * 4;
            *(float4*)&As[ksq][bb][kq * 4] = *(const float4*)(h1n + (size_t)bb * H_ + kg);
        }
        __syncthreads();

        int kbase = ks * 256 + c * 64;
        const float4* w0 = (const float4*)(w_in + (size_t)j * H_ + kbase);
        const float4* A4 = (const float4*)&As[ks][b][0];
        #pragma unroll
        for (int kk = 0; kk < 16; ++kk) {
            float4 a  = A4[kk];
            float4 q0 = w0[kk];
            acc += a.x * q0.x + a.y * q0.y + a.z * q0.z + a.w * q0.w;
        }
        __syncthreads();
    }

    int idx = tid & 63;
    if (ks > 0) red[ks - 1][idx] = acc;
    __syncthreads();
    if (ks == 0) {
        acc += red[0][idx] + red[1][idx] + red[2][idx];
        q_out[b * H_ + j] = acc;
    }
}

// ---------------------------------------------------------------------------
// scores[b][s] = x[b] . base[b][s]   grid 512 = b(32) x stile(16), block 256.
// ---------------------------------------------------------------------------
__global__ __launch_bounds__(256) void k_scores(
    const float* __restrict__ x_in, const float* __restrict__ base,
    float* __restrict__ sc_out)
{
    __shared__ float q_lds[1024];

    int b  = blockIdx.x >> 4;
    int st = blockIdx.x & 15;
    int tid  = threadIdx.x;
    int lane = tid & 63;
    int wv   = tid >> 6;

    ((float4*)q_lds)[tid] = ((const float4*)(x_in + (size_t)b * H_))[tid];
    __syncthreads();

    float4 q4[4];
    #pragma unroll
    for (int i = 0; i < 4; ++i) q4[i] = ((const float4*)q_lds)[lane + 64 * i];

    const float* mb = base + (size_t)b * S_ * H_;
    #pragma unroll
    for (int ss = 0; ss < 4; ++ss) {
        int s = st * 16 + wv * 4 + ss;
        const float4* mr = (const float4*)(mb + (size_t)s * H_);
        float a = 0.0f;
        #pragma unroll
        for (int i = 0; i < 4; ++i) {
            float4 m = mr[lane + 64 * i];
            a += q4[i].x * m.x + q4[i].y * m.y + q4[i].z * m.z + q4[i].w * m.w;
        }
        #pragma unroll
        for (int o = 32; o > 0; o >>= 1) a += __shfl_down(a, o);
        if (lane == 0) sc_out[b * S_ + s] = a;
    }
}

// ---------------------------------------------------------------------------
// ctx: local masked softmax of scores + weighted sum.  grid 512, block 256
// ---------------------------------------------------------------------------
__global__ __launch_bounds__(256) void k_ctx(
    const float* __restrict__ sc_in, const float* __restrict__ mem,
    const int* __restrict__ masks,
    float* __restrict__ ctx, float* __restrict__ attn_out, int t)
{
    __shared__ float aw[256];
    __shared__ float red2[4][64];

    int b  = blockIdx.x >> 4;
    int ht = blockIdx.x & 15;
    int tid  = threadIdx.x;
    int lane = tid & 63;
    int wv   = tid >> 6;

    if (wv == 0) {
        int m = 0;
        #pragma unroll
        for (int i = 0; i < 4; ++i) m += masks[b * S_ + lane * 4 + i];
        #pragma unroll
        for (int o = 32; o > 0; o >>= 1) m += __shfl_down(m, o);
        int len = __shfl(m, 0);

        float v[4];
        float mx = -1e30f;
        #pragma unroll
        for (int i = 0; i < 4; ++i) {
            int s = lane + 64 * i;
            float xv = (s < len) ? sc_in[b * S_ + s] : -1e9f;
            v[i] = xv;
            mx = fmaxf(mx, xv);
        }
        #pragma unroll
        for (int o = 32; o > 0; o >>= 1) mx = fmaxf(mx, __shfl_xor(mx, o));
        float sm = 0.0f;
        #pragma unroll
        for (int i = 0; i < 4; ++i) { v[i] = __expf(v[i] - mx); sm += v[i]; }
        #pragma unroll
        for (int o = 32; o > 0; o >>= 1) sm += __shfl_xor(sm, o);
        float inv = 1.0f / sm;
        #pragma unroll
        for (int i = 0; i < 4; ++i) {
            int s = lane + 64 * i;
            float w = v[i] * inv;
            aw[s] = w;
            if (ht == 0) attn_out[((size_t)b * T_ + t) * S_ + s] = w;
        }
    }
    __syncthreads();

    int h = ht * 64 + lane;
    const float* mb = mem + (size_t)b * S_ * H_;
    float a = 0.0f;
    #pragma unroll 8
    for (int ss = 0; ss < 64; ++ss) {
        int s = wv * 64 + ss;
        a += aw[s] * mb[(size_t)s * H_ + h];
    }
    red2[wv][lane] = a;
    __syncthreads();
    if (tid < 64) {
        float r = red2[0][tid] + red2[1][tid] + red2[2][tid] + red2[3][tid];
        ctx[b * H_ + ht * 64 + tid] = r;
    }
}

// -------- out = tanh([ctx | h1n] @ w_out^T), pipelined ---------------------
__global__ __launch_bounds__(256) void k_out(
    const float* __restrict__ w_out, const float* __restrict__ ctx,
    const float* __restrict__ h1n,
    float* __restrict__ feedn, float* __restrict__ dout, int t)
{
    __shared__ float As[2][4][32][68];
    __shared__ float red[3][64];

    int tid = threadIdx.x;
    int b  = tid & 31;
    int jl = (tid >> 5) & 1;
    int ks = tid >> 6;
    int j  = blockIdx.x * 2 + jl;

    float acc = 0.0f;

    float4 r[8];
    #pragma unroll
    for (int i = 0; i < 8; ++i) {
        int q   = tid + i * 256;
        int ksq = q >> 9, rem = q & 511, bb = rem >> 4, kq = rem & 15;
        int kg  = ksq * 512 + kq * 4;
        const float* src = (kg < 1024) ? (ctx + (size_t)bb * H_ + kg)
                                       : (h1n + (size_t)bb * H_ + (kg - 1024));
        r[i] = *(const float4*)src;
    }

    for (int c = 0; c < 8; ++c) {
        const int buf = c & 1;
        #pragma unroll
        for (int i = 0; i < 8; ++i) {
            int q   = tid + i * 256;
            int ksq = q >> 9, rem = q & 511, bb = rem >> 4, kq = rem & 15;
            *(float4*)&As[buf][ksq][bb][kq * 4] = r[i];
        }
        __syncthreads();

        if (c < 7) {
            #pragma unroll
            for (int i = 0; i < 8; ++i) {
                int q   = tid + i * 256;
                int ksq = q >> 9, rem = q & 511, bb = rem >> 4, kq = rem & 15;
                int kg  = ksq * 512 + (c + 1) * 64 + kq * 4;
                const float* src = (kg < 1024) ? (ctx + (size_t)bb * H_ + kg)
                                               : (h1n + (size_t)bb * H_ + (kg - 1024));
                r[i] = *(const float4*)src;
            }
        }

        const float4* w0 = (const float4*)(w_out + (size_t)j * 2048 + ks * 512 + c * 64);
        const float4* A4 = (const float4*)&As[buf][ks][b][0];
        #pragma unroll
        for (int kk = 0; kk < 16; ++kk) {
            float4 a  = A4[kk];
            float4 q0 = w0[kk];
            acc += a.x * q0.x + a.y * q0.y + a.z * q0.z + a.w * q0.w;
        }
    }

    __syncthreads();
    int idx = tid & 63;
    if (ks > 0) red[ks - 1][idx] = acc;
    __syncthreads();
    if (ks == 0) {
        acc += red[0][idx] + red[1][idx] + red[2][idx];
        float o = tanh_(acc);
        feedn[b * H_ + j] = o;
        dout[((size_t)b * T_ + t) * H_ + j] = o;
    }
}

// ---------------------------------------------------------------------------
extern "C" void kernel_launch(void* const* d_in, const int* in_sizes, int n_in,
                              void* d_out, int out_size, void* d_ws, size_t ws_size,
                              hipStream_t stream) {
    const int*   tgt    = (const int*)  d_in[0];
    const float* mem    = (const float*)d_in[1];
    const int*   masks  = (const int*)  d_in[2];
    const float* h0in   = (const float*)d_in[3];
    const float* c0in   = (const float*)d_in[4];
    const float* emb    = (const float*)d_in[5];
    const float* w_ih0  = (const float*)d_in[6];
    const float* w_hh0  = (const float*)d_in[7];
    const float* b_ih0  = (const float*)d_in[8];
    const float* b_hh0  = (const float*)d_in[9];
    const float* w_ih1  = (const float*)d_in[10];
    const float* w_hh1  = (const float*)d_in[11];
    const float* b_ih1  = (const float*)d_in[12];
    const float* b_hh1  = (const float*)d_in[13];
    const float* w_in   = (const float*)d_in[14];
    const float* w_out  = (const float*)d_in[15];

    float* dout     = (float*)d_out;
    float* attn_out = dout + (size_t)B_ * T_ * H_;

    float* ws   = (float*)d_ws;
    float* h0s  = ws;              // [2][B*H]
    float* c0s  = h0s  + 2 * BH_;  // [2][B*H]
    float* h1s  = c0s  + 2 * BH_;  // [2][B*H]
    float* c1s  = h1s  + 2 * BH_;  // [2][B*H]
    float* feed = c1s  + 2 * BH_;  // [2][B*H]
    float* qctx = feed + 2 * BH_;  // [B*H]   (ctx; fallback also uses as q)
    float* scw  = qctx + BH_;      // [B*S]
    float* pmem = scw  + B_ * S_;  // [B*S*H] = 33.5 MB

    const size_t need = ((size_t)(11 * BH_ + B_ * S_) + (size_t)B_ * S_ * H_) * 4;
    const bool use_pmem = (ws_size >= need);

    k_init<<<128, 256, 0, stream>>>(h0in, c0in, h0s, c0s, h1s, c1s, feed);

    if (use_pmem) {
        k_pmem<<<dim3(128, 16), 256, 0, stream>>>(mem, w_in, pmem);

        for (int t = 0; t < T_; ++t) {
            int cur = t & 1, nxt = cur ^ 1;
            k_lstm0<<<512, 256, 0, stream>>>(tgt, emb, w_ih0, w_hh0, b_ih0, b_hh0,
                                             feed + cur * BH_, h0s + cur * BH_, c0s + cur * BH_,
                                             h0s + nxt * BH_, c0s + nxt * BH_, t);
            k_lstm1<<<512, 256, 0, stream>>>(w_ih1, w_hh1, b_ih1, b_hh1,
                                             h0s + nxt * BH_, h1s + cur * BH_, c1s + cur * BH_,
                                             h1s + nxt * BH_, c1s + nxt * BH_);
            k_scores<<<512, 256, 0, stream>>>(h1s + nxt * BH_, pmem, scw);
            k_ctx<<<512, 256, 0, stream>>>(scw, mem, masks, qctx, attn_out, t);
            k_out<<<512, 256, 0, stream>>>(w_out, qctx, h1s + nxt * BH_,
                                           feed + nxt * BH_, dout, t);
        }
    } else {
        for (int t = 0; t < T_; ++t) {
            int cur = t & 1, nxt = cur ^ 1;
            k_lstm0<<<512, 256, 0, stream>>>(tgt, emb, w_ih0, w_hh0, b_ih0, b_hh0,
                                             feed + cur * BH_, h0s + cur * BH_, c0s + cur * BH_,
                                             h0s + nxt * BH_, c0s + nxt * BH_, t);
            k_lstm1<<<512, 256, 0, stream>>>(w_ih1, w_hh1, b_ih1, b_hh1,
                                             h0s + nxt * BH_, h1s + cur * BH_, c1s + cur * BH_,
                                             h1s + nxt * BH_, c1s + nxt * BH_);
            k_q<<<512, 256, 0, stream>>>(w_in, h1s + nxt * BH_, qctx);
            k_scores<<<512, 256, 0, stream>>>(qctx, mem, scw);
            k_ctx<<<512, 256, 0, stream>>>(scw, mem, masks, qctx, attn_out, t);
            k_out<<<512, 256, 0, stream>>>(w_out, qctx, h1s + nxt * BH_,
                                           feed + nxt * BH_, dout, t);
        }
    }
}

// Round 10
// 9279.197 us; speedup vs baseline: 1.4249x; 1.4249x over previous
//
#include <hip/hip_runtime.h>
#include <math.h>

#define B_ 32
#define T_ 64
#define S_ 256
#define H_ 1024
#define E_ 512
#define BH_ (B_ * H_)

__device__ __forceinline__ float sigm(float x) {
    return 1.0f / (1.0f + __expf(-x));
}
__device__ __forceinline__ float tanh_(float x) {
    x = fminf(15.0f, fmaxf(-15.0f, x));
    float e = __expf(-2.0f * x);
    return (1.0f - e) / (1.0f + e);
}

// ---------------------------------------------------------------------------
// init: state ping-pong slot 0 + zero input feed
// ---------------------------------------------------------------------------
__global__ void k_init(const float* __restrict__ h0in, const float* __restrict__ c0in,
                       float* h0s, float* c0s, float* h1s, float* c1s, float* feed) {
    int i = blockIdx.x * 256 + threadIdx.x;
    if (i < BH_) {
        h0s[i]  = h0in[i];
        h1s[i]  = h0in[BH_ + i];
        c0s[i]  = c0in[i];
        c1s[i]  = c0in[BH_ + i];
        feed[i] = 0.0f;
    }
}

// ---------------------------------------------------------------------------
// pmem[r][k] = sum_j mem[r][j] * w_in[j][k]   (r = b*S+s; time-invariant)
// grid (128, 16), block 256.  64x64 tile, K-chunk 32, 4x4 outputs/thread.
// ---------------------------------------------------------------------------
__global__ __launch_bounds__(256) void k_pmem(
    const float* __restrict__ mem, const float* __restrict__ w_in,
    float* __restrict__ pmem)
{
    __shared__ float As[64][36];   // [row][k]  +pad
    __shared__ float Bs[32][68];   // [k][col]  +pad

    const int tid = threadIdx.x;
    const int rt = blockIdx.x * 64;
    const int ct = blockIdx.y * 64;
    const int tx = tid & 15;       // col group
    const int ty = tid >> 4;       // row group

    float acc[4][4] = {{0.f}};

    for (int jc = 0; jc < 1024; jc += 32) {
        #pragma unroll
        for (int i = 0; i < 2; ++i) {
            int s2  = tid + i * 256;            // 0..511
            int row = s2 >> 3, kq = s2 & 7;
            *(float4*)&As[row][kq * 4] =
                *(const float4*)(mem + (size_t)(rt + row) * 1024 + jc + kq * 4);
        }
        #pragma unroll
        for (int i = 0; i < 2; ++i) {
            int s2 = tid + i * 256;
            int kk = s2 >> 4, cq = s2 & 15;
            *(float4*)&Bs[kk][cq * 4] =
                *(const float4*)(w_in + (size_t)(jc + kk) * 1024 + ct + cq * 4);
        }
        __syncthreads();

        #pragma unroll
        for (int kk = 0; kk < 32; ++kk) {
            float a0 = As[ty * 4 + 0][kk], a1 = As[ty * 4 + 1][kk];
            float a2 = As[ty * 4 + 2][kk], a3 = As[ty * 4 + 3][kk];
            float b0 = Bs[kk][tx * 4 + 0], b1 = Bs[kk][tx * 4 + 1];
            float b2 = Bs[kk][tx * 4 + 2], b3 = Bs[kk][tx * 4 + 3];
            acc[0][0] += a0 * b0; acc[0][1] += a0 * b1; acc[0][2] += a0 * b2; acc[0][3] += a0 * b3;
            acc[1][0] += a1 * b0; acc[1][1] += a1 * b1; acc[1][2] += a1 * b2; acc[1][3] += a1 * b3;
            acc[2][0] += a2 * b0; acc[2][1] += a2 * b1; acc[2][2] += a2 * b2; acc[2][3] += a2 * b3;
            acc[3][0] += a3 * b0; acc[3][1] += a3 * b1; acc[3][2] += a3 * b2; acc[3][3] += a3 * b3;
        }
        __syncthreads();
    }

    #pragma unroll
    for (int i = 0; i < 4; ++i) {
        float4 v = make_float4(acc[i][0], acc[i][1], acc[i][2], acc[i][3]);
        *(float4*)(pmem + (size_t)(rt + ty * 4 + i) * 1024 + ct + tx * 4) = v;
    }
}

// ===========================================================================
// GEMM kernels (round-2 inner loop, 128-k staged chunks -> half the barriers)
// grid 512, block 256 = 32 b x 2 jl x 4 ks.
// ===========================================================================

// -------- LSTM layer 0: K = 2560 = [emb 512 | feed 1024 | h0 1024] ---------
__global__ __launch_bounds__(256) void k_lstm0(
    const int* __restrict__ tgt, const float* __restrict__ emb,
    const float* __restrict__ w_ih0, const float* __restrict__ w_hh0,
    const float* __restrict__ b_ih0, const float* __restrict__ b_hh0,
    const float* __restrict__ feed, const float* __restrict__ h0c,
    const float* __restrict__ c0c,
    float* __restrict__ h0n, float* __restrict__ c0n, int t)
{
    __shared__ float As[4][32][132];    // 128-k chunk +4 pad = 67.6 KB
    __shared__ float red[3][64][4];
    __shared__ int   tok[32];

    int tid = threadIdx.x;
    int b  = tid & 31;
    int jl = (tid >> 5) & 1;
    int ks = tid >> 6;
    int j  = blockIdx.x * 2 + jl;

    if (tid < 32) tok[tid] = tgt[tid * T_ + t];
    __syncthreads();

    float acc0, acc1, acc2, acc3;
    if (ks == 0) {
        acc0 = b_ih0[0 * H_ + j] + b_hh0[0 * H_ + j];
        acc1 = b_ih0[1 * H_ + j] + b_hh0[1 * H_ + j];
        acc2 = b_ih0[2 * H_ + j] + b_hh0[2 * H_ + j];
        acc3 = b_ih0[3 * H_ + j] + b_hh0[3 * H_ + j];
    } else {
        acc0 = acc1 = acc2 = acc3 = 0.0f;
    }

    for (int c = 0; c < 5; ++c) {          // 5 chunks of 128 k per ks
        // stage [4 ks][32 b][128 k] = 4096 float4, 16 per thread
        #pragma unroll
        for (int i = 0; i < 16; ++i) {
            int q   = tid + i * 256;
            int ksq = q >> 10;
            int rem = q & 1023;
            int bb  = rem >> 5;
            int kq  = rem & 31;
            int kg  = ksq * 640 + c * 128 + kq * 4;
            const float* src;
            if (kg < 512)        src = emb  + (size_t)tok[bb] * E_ + kg;
            else if (kg < 1536)  src = feed + (size_t)bb * H_ + (kg - 512);
            else                 src = h0c  + (size_t)bb * H_ + (kg - 1536);
            *(float4*)&As[ksq][bb][kq * 4] = *(const float4*)src;
        }
        __syncthreads();

        #pragma unroll
        for (int h2 = 0; h2 < 2; ++h2) {   // two 64-k compute halves, no barrier
            int kbase = ks * 640 + c * 128 + h2 * 64;
            const float4 *w0, *w1, *w2, *w3;
            if (kbase < 1536) {
                w0 = (const float4*)(w_ih0 + (size_t)(0 * H_ + j) * 1536 + kbase);
                w1 = (const float4*)(w_ih0 + (size_t)(1 * H_ + j) * 1536 + kbase);
                w2 = (const float4*)(w_ih0 + (size_t)(2 * H_ + j) * 1536 + kbase);
                w3 = (const float4*)(w_ih0 + (size_t)(3 * H_ + j) * 1536 + kbase);
            } else {
                int kb = kbase - 1536;
                w0 = (const float4*)(w_hh0 + (size_t)(0 * H_ + j) * 1024 + kb);
                w1 = (const float4*)(w_hh0 + (size_t)(1 * H_ + j) * 1024 + kb);
                w2 = (const float4*)(w_hh0 + (size_t)(2 * H_ + j) * 1024 + kb);
                w3 = (const float4*)(w_hh0 + (size_t)(3 * H_ + j) * 1024 + kb);
            }
            const float4* A4 = (const float4*)&As[ks][b][h2 * 64];
            #pragma unroll
            for (int kk = 0; kk < 16; ++kk) {
                float4 a  = A4[kk];
                float4 q0 = w0[kk], q1 = w1[kk], q2 = w2[kk], q3 = w3[kk];
                acc0 += a.x * q0.x + a.y * q0.y + a.z * q0.z + a.w * q0.w;
                acc1 += a.x * q1.x + a.y * q1.y + a.z * q1.z + a.w * q1.w;
                acc2 += a.x * q2.x + a.y * q2.y + a.z * q2.z + a.w * q2.w;
                acc3 += a.x * q3.x + a.y * q3.y + a.z * q3.z + a.w * q3.w;
            }
        }
        __syncthreads();
    }

    int idx = tid & 63;
    if (ks > 0) {
        red[ks - 1][idx][0] = acc0; red[ks - 1][idx][1] = acc1;
        red[ks - 1][idx][2] = acc2; red[ks - 1][idx][3] = acc3;
    }
    __syncthreads();
    if (ks == 0) {
        #pragma unroll
        for (int r = 0; r < 3; ++r) {
            acc0 += red[r][idx][0]; acc1 += red[r][idx][1];
            acc2 += red[r][idx][2]; acc3 += red[r][idx][3];
        }
        float co = c0c[b * H_ + j];
        float cn = sigm(acc1) * co + sigm(acc0) * tanh_(acc2);
        float hn = sigm(acc3) * tanh_(cn);
        c0n[b * H_ + j] = cn;
        h0n[b * H_ + j] = hn;
    }
}

// -------- LSTM layer 1: K = 2048 = [h0n 1024 | h1 1024] --------------------
__global__ __launch_bounds__(256) void k_lstm1(
    const float* __restrict__ w_ih1, const float* __restrict__ w_hh1,
    const float* __restrict__ b_ih1, const float* __restrict__ b_hh1,
    const float* __restrict__ x, const float* __restrict__ h1c,
    const float* __restrict__ c1c,
    float* __restrict__ h1n, float* __restrict__ c1n)
{
    __shared__ float As[4][32][132];
    __shared__ float red[3][64][4];

    int tid = threadIdx.x;
    int b  = tid & 31;
    int jl = (tid >> 5) & 1;
    int ks = tid >> 6;
    int j  = blockIdx.x * 2 + jl;

    float acc0, acc1, acc2, acc3;
    if (ks == 0) {
        acc0 = b_ih1[0 * H_ + j] + b_hh1[0 * H_ + j];
        acc1 = b_ih1[1 * H_ + j] + b_hh1[1 * H_ + j];
        acc2 = b_ih1[2 * H_ + j] + b_hh1[2 * H_ + j];
        acc3 = b_ih1[3 * H_ + j] + b_hh1[3 * H_ + j];
    } else {
        acc0 = acc1 = acc2 = acc3 = 0.0f;
    }

    for (int c = 0; c < 4; ++c) {          // 4 chunks of 128 k per ks
        #pragma unroll
        for (int i = 0; i < 16; ++i) {
            int q   = tid + i * 256;
            int ksq = q >> 10;
            int rem = q & 1023;
            int bb  = rem >> 5;
            int kq  = rem & 31;
            int kg  = ksq * 512 + c * 128 + kq * 4;
            const float* src = (kg < 1024) ? (x + (size_t)bb * H_ + kg)
                                           : (h1c + (size_t)bb * H_ + (kg - 1024));
            *(float4*)&As[ksq][bb][kq * 4] = *(const float4*)src;
        }
        __syncthreads();

        #pragma unroll
        for (int h2 = 0; h2 < 2; ++h2) {
            int kbase = ks * 512 + c * 128 + h2 * 64;
            const float* wb;
            int ko;
            if (kbase < 1024) { wb = w_ih1; ko = kbase; }
            else              { wb = w_hh1; ko = kbase - 1024; }
            const float4* w0 = (const float4*)(wb + (size_t)(0 * H_ + j) * H_ + ko);
            const float4* w1 = (const float4*)(wb + (size_t)(1 * H_ + j) * H_ + ko);
            const float4* w2 = (const float4*)(wb + (size_t)(2 * H_ + j) * H_ + ko);
            const float4* w3 = (const float4*)(wb + (size_t)(3 * H_ + j) * H_ + ko);
            const float4* A4 = (const float4*)&As[ks][b][h2 * 64];
            #pragma unroll
            for (int kk = 0; kk < 16; ++kk) {
                float4 a  = A4[kk];
                float4 q0 = w0[kk], q1 = w1[kk], q2 = w2[kk], q3 = w3[kk];
                acc0 += a.x * q0.x + a.y * q0.y + a.z * q0.z + a.w * q0.w;
                acc1 += a.x * q1.x + a.y * q1.y + a.z * q1.z + a.w * q1.w;
                acc2 += a.x * q2.x + a.y * q2.y + a.z * q2.z + a.w * q2.w;
                acc3 += a.x * q3.x + a.y * q3.y + a.z * q3.z + a.w * q3.w;
            }
        }
        __syncthreads();
    }

    int idx = tid & 63;
    if (ks > 0) {
        red[ks - 1][idx][0] = acc0; red[ks - 1][idx][1] = acc1;
        red[ks - 1][idx][2] = acc2; red[ks - 1][idx][3] = acc3;
    }
    __syncthreads();
    if (ks == 0) {
        #pragma unroll
        for (int r = 0; r < 3; ++r) {
            acc0 += red[r][idx][0]; acc1 += red[r][idx][1];
            acc2 += red[r][idx][2]; acc3 += red[r][idx][3];
        }
        float co = c1c[b * H_ + j];
        float cn = sigm(acc1) * co + sigm(acc0) * tanh_(acc2);
        float hn = sigm(acc3) * tanh_(cn);
        c1n[b * H_ + j] = cn;
        h1n[b * H_ + j] = hn;
    }
}

// -------- q = h1n @ w_in^T (FALLBACK PATH ONLY) ----------------------------
__global__ __launch_bounds__(256) void k_q(
    const float* __restrict__ w_in, const float* __restrict__ h1n,
    float* __restrict__ q_out)
{
    __shared__ float As[4][32][68];
    __shared__ float red[3][64];

    int tid = threadIdx.x;
    int b  = tid & 31;
    int jl = (tid >> 5) & 1;
    int ks = tid >> 6;
    int j  = blockIdx.x * 2 + jl;

    float acc = 0.0f;
    for (int c = 0; c < 4; ++c) {
        #pragma unroll
        for (int i = 0; i < 8; ++i) {
            int q   = tid + i * 256;
            int ksq = q >> 9;
            int rem = q & 511;
            int bb  = rem >> 4;
            int kq  = rem & 15;
            int kg  = ksq * 256 + c * 64 + kq * 4;
            *(float4*)&As[ksq][bb][kq * 4] = *(const float4*)(h1n + (size_t)bb * H_ + kg);
        }
        __syncthreads();

        int kbase = ks * 256 + c * 64;
        const float4* w0 = (const float4*)(w_in + (size_t)j * H_ + kbase);
        const float4* A4 = (const float4*)&As[ks][b][0];
        #pragma unroll
        for (int kk = 0; kk < 16; ++kk) {
            float4 a  = A4[kk];
            float4 q0 = w0[kk];
            acc += a.x * q0.x + a.y * q0.y + a.z * q0.z + a.w * q0.w;
        }
        __syncthreads();
    }

    int idx = tid & 63;
    if (ks > 0) red[ks - 1][idx] = acc;
    __syncthreads();
    if (ks == 0) {
        acc += red[0][idx] + red[1][idx] + red[2][idx];
        q_out[b * H_ + j] = acc;
    }
}

// ---------------------------------------------------------------------------
// scores[b][s] = x[b] . base[b][s]   grid 512 = b(32) x stile(16), block 256.
// ---------------------------------------------------------------------------
__global__ __launch_bounds__(256) void k_scores(
    const float* __restrict__ x_in, const float* __restrict__ base,
    float* __restrict__ sc_out)
{
    __shared__ float q_lds[1024];

    int b  = blockIdx.x >> 4;
    int st = blockIdx.x & 15;
    int tid  = threadIdx.x;
    int lane = tid & 63;
    int wv   = tid >> 6;

    ((float4*)q_lds)[tid] = ((const float4*)(x_in + (size_t)b * H_))[tid];
    __syncthreads();

    float4 q4[4];
    #pragma unroll
    for (int i = 0; i < 4; ++i) q4[i] = ((const float4*)q_lds)[lane + 64 * i];

    const float* mb = base + (size_t)b * S_ * H_;
    #pragma unroll
    for (int ss = 0; ss < 4; ++ss) {
        int s = st * 16 + wv * 4 + ss;
        const float4* mr = (const float4*)(mb + (size_t)s * H_);
        float a = 0.0f;
        #pragma unroll
        for (int i = 0; i < 4; ++i) {
            float4 m = mr[lane + 64 * i];
            a += q4[i].x * m.x + q4[i].y * m.y + q4[i].z * m.z + q4[i].w * m.w;
        }
        #pragma unroll
        for (int o = 32; o > 0; o >>= 1) a += __shfl_down(a, o);
        if (lane == 0) sc_out[b * S_ + s] = a;
    }
}

// ---------------------------------------------------------------------------
// ctx: local masked softmax of scores + weighted sum.  grid 512, block 256
// ---------------------------------------------------------------------------
__global__ __launch_bounds__(256) void k_ctx(
    const float* __restrict__ sc_in, const float* __restrict__ mem,
    const int* __restrict__ masks,
    float* __restrict__ ctx, float* __restrict__ attn_out, int t)
{
    __shared__ float aw[256];
    __shared__ float red2[4][64];

    int b  = blockIdx.x >> 4;
    int ht = blockIdx.x & 15;
    int tid  = threadIdx.x;
    int lane = tid & 63;
    int wv   = tid >> 6;

    if (wv == 0) {
        int m = 0;
        #pragma unroll
        for (int i = 0; i < 4; ++i) m += masks[b * S_ + lane * 4 + i];
        #pragma unroll
        for (int o = 32; o > 0; o >>= 1) m += __shfl_down(m, o);
        int len = __shfl(m, 0);

        float v[4];
        float mx = -1e30f;
        #pragma unroll
        for (int i = 0; i < 4; ++i) {
            int s = lane + 64 * i;
            float xv = (s < len) ? sc_in[b * S_ + s] : -1e9f;
            v[i] = xv;
            mx = fmaxf(mx, xv);
        }
        #pragma unroll
        for (int o = 32; o > 0; o >>= 1) mx = fmaxf(mx, __shfl_xor(mx, o));
        float sm = 0.0f;
        #pragma unroll
        for (int i = 0; i < 4; ++i) { v[i] = __expf(v[i] - mx); sm += v[i]; }
        #pragma unroll
        for (int o = 32; o > 0; o >>= 1) sm += __shfl_xor(sm, o);
        float inv = 1.0f / sm;
        #pragma unroll
        for (int i = 0; i < 4; ++i) {
            int s = lane + 64 * i;
            float w = v[i] * inv;
            aw[s] = w;
            if (ht == 0) attn_out[((size_t)b * T_ + t) * S_ + s] = w;
        }
    }
    __syncthreads();

    int h = ht * 64 + lane;
    const float* mb = mem + (size_t)b * S_ * H_;
    float a = 0.0f;
    #pragma unroll 8
    for (int ss = 0; ss < 64; ++ss) {
        int s = wv * 64 + ss;
        a += aw[s] * mb[(size_t)s * H_ + h];
    }
    red2[wv][lane] = a;
    __syncthreads();
    if (tid < 64) {
        float r = red2[0][tid] + red2[1][tid] + red2[2][tid] + red2[3][tid];
        ctx[b * H_ + ht * 64 + tid] = r;
    }
}

// -------- out = tanh([ctx | h1n] @ w_out^T) : K = 2048 ---------------------
__global__ __launch_bounds__(256) void k_out(
    const float* __restrict__ w_out, const float* __restrict__ ctx,
    const float* __restrict__ h1n,
    float* __restrict__ feedn, float* __restrict__ dout, int t)
{
    __shared__ float As[4][32][132];
    __shared__ float red[3][64];

    int tid = threadIdx.x;
    int b  = tid & 31;
    int jl = (tid >> 5) & 1;
    int ks = tid >> 6;
    int j  = blockIdx.x * 2 + jl;

    float acc = 0.0f;
    for (int c = 0; c < 4; ++c) {          // 4 chunks of 128 k per ks
        #pragma unroll
        for (int i = 0; i < 16; ++i) {
            int q   = tid + i * 256;
            int ksq = q >> 10;
            int rem = q & 1023;
            int bb  = rem >> 5;
            int kq  = rem & 31;
            int kg  = ksq * 512 + c * 128 + kq * 4;
            const float* src = (kg < 1024) ? (ctx + (size_t)bb * H_ + kg)
                                           : (h1n + (size_t)bb * H_ + (kg - 1024));
            *(float4*)&As[ksq][bb][kq * 4] = *(const float4*)src;
        }
        __syncthreads();

        #pragma unroll
        for (int h2 = 0; h2 < 2; ++h2) {
            const float4* w0 = (const float4*)(w_out + (size_t)j * 2048
                                               + ks * 512 + c * 128 + h2 * 64);
            const float4* A4 = (const float4*)&As[ks][b][h2 * 64];
            #pragma unroll
            for (int kk = 0; kk < 16; ++kk) {
                float4 a  = A4[kk];
                float4 q0 = w0[kk];
                acc += a.x * q0.x + a.y * q0.y + a.z * q0.z + a.w * q0.w;
            }
        }
        __syncthreads();
    }

    int idx = tid & 63;
    if (ks > 0) red[ks - 1][idx] = acc;
    __syncthreads();
    if (ks == 0) {
        acc += red[0][idx] + red[1][idx] + red[2][idx];
        float o = tanh_(acc);
        feedn[b * H_ + j] = o;
        dout[((size_t)b * T_ + t) * H_ + j] = o;
    }
}

// ---------------------------------------------------------------------------
extern "C" void kernel_launch(void* const* d_in, const int* in_sizes, int n_in,
                              void* d_out, int out_size, void* d_ws, size_t ws_size,
                              hipStream_t stream) {
    const int*   tgt    = (const int*)  d_in[0];
    const float* mem    = (const float*)d_in[1];
    const int*   masks  = (const int*)  d_in[2];
    const float* h0in   = (const float*)d_in[3];
    const float* c0in   = (const float*)d_in[4];
    const float* emb    = (const float*)d_in[5];
    const float* w_ih0  = (const float*)d_in[6];
    const float* w_hh0  = (const float*)d_in[7];
    const float* b_ih0  = (const float*)d_in[8];
    const float* b_hh0  = (const float*)d_in[9];
    const float* w_ih1  = (const float*)d_in[10];
    const float* w_hh1  = (const float*)d_in[11];
    const float* b_ih1  = (const float*)d_in[12];
    const float* b_hh1  = (const float*)d_in[13];
    const float* w_in   = (const float*)d_in[14];
    const float* w_out  = (const float*)d_in[15];

    float* dout     = (float*)d_out;
    float* attn_out = dout + (size_t)B_ * T_ * H_;

    float* ws   = (float*)d_ws;
    float* h0s  = ws;              // [2][B*H]
    float* c0s  = h0s  + 2 * BH_;  // [2][B*H]
    float* h1s  = c0s  + 2 * BH_;  // [2][B*H]
    float* c1s  = h1s  + 2 * BH_;  // [2][B*H]
    float* feed = c1s  + 2 * BH_;  // [2][B*H]
    float* qctx = feed + 2 * BH_;  // [B*H]   (ctx; fallback also uses as q)
    float* scw  = qctx + BH_;      // [B*S]
    float* pmem = scw  + B_ * S_;  // [B*S*H] = 33.5 MB

    const size_t need = ((size_t)(11 * BH_ + B_ * S_) + (size_t)B_ * S_ * H_) * 4;
    const bool use_pmem = (ws_size >= need);

    k_init<<<128, 256, 0, stream>>>(h0in, c0in, h0s, c0s, h1s, c1s, feed);

    if (use_pmem) {
        k_pmem<<<dim3(128, 16), 256, 0, stream>>>(mem, w_in, pmem);

        for (int t = 0; t < T_; ++t) {
            int cur = t & 1, nxt = cur ^ 1;
            k_lstm0<<<512, 256, 0, stream>>>(tgt, emb, w_ih0, w_hh0, b_ih0, b_hh0,
                                             feed + cur * BH_, h0s + cur * BH_, c0s + cur * BH_,
                                             h0s + nxt * BH_, c0s + nxt * BH_, t);
            k_lstm1<<<512, 256, 0, stream>>>(w_ih1, w_hh1, b_ih1, b_hh1,
                                             h0s + nxt * BH_, h1s + cur * BH_, c1s + cur * BH_,
                                             h1s + nxt * BH_, c1s + nxt * BH_);
            k_scores<<<512, 256, 0, stream>>>(h1s + nxt * BH_, pmem, scw);
            k_ctx<<<512, 256, 0, stream>>>(scw, mem, masks, qctx, attn_out, t);
            k_out<<<512, 256, 0, stream>>>(w_out, qctx, h1s + nxt * BH_,
                                           feed + nxt * BH_, dout, t);
        }
    } else {
        for (int t = 0; t < T_; ++t) {
            int cur = t & 1, nxt = cur ^ 1;
            k_lstm0<<<512, 256, 0, stream>>>(tgt, emb, w_ih0, w_hh0, b_ih0, b_hh0,
                                             feed + cur * BH_, h0s + cur * BH_, c0s + cur * BH_,
                                             h0s + nxt * BH_, c0s + nxt * BH_, t);
            k_lstm1<<<512, 256, 0, stream>>>(w_ih1, w_hh1, b_ih1, b_hh1,
                                             h0s + nxt * BH_, h1s + cur * BH_, c1s + cur * BH_,
                                             h1s + nxt * BH_, c1s + nxt * BH_);
            k_q<<<512, 256, 0, stream>>>(w_in, h1s + nxt * BH_, qctx);
            k_scores<<<512, 256, 0, stream>>>(qctx, mem, scw);
            k_ctx<<<512, 256, 0, stream>>>(scw, mem, masks, qctx, attn_out, t);
            k_out<<<512, 256, 0, stream>>>(w_out, qctx, h1s + nxt * BH_,
                                           feed + nxt * BH_, dout, t);
        }
    }
}

// Round 11
// 8318.291 us; speedup vs baseline: 1.5895x; 1.1155x over previous
//
#include <hip/hip_runtime.h>
#include <math.h>

#define B_ 32
#define T_ 64
#define S_ 256
#define H_ 1024
#define E_ 512
#define BH_ (B_ * H_)

__device__ __forceinline__ float sigm(float x) {
    return 1.0f / (1.0f + __expf(-x));
}
__device__ __forceinline__ float tanh_(float x) {
    x = fminf(15.0f, fmaxf(-15.0f, x));
    float e = __expf(-2.0f * x);
    return (1.0f - e) / (1.0f + e);
}

// ---------------------------------------------------------------------------
// gap probe: empty kernel, 1 block. Measures per-dispatch overhead in-graph.
// ---------------------------------------------------------------------------
__global__ void k_nop() {}

// ---------------------------------------------------------------------------
// init: state ping-pong slot 0 + zero input feed
// ---------------------------------------------------------------------------
__global__ void k_init(const float* __restrict__ h0in, const float* __restrict__ c0in,
                       float* h0s, float* c0s, float* h1s, float* c1s, float* feed) {
    int i = blockIdx.x * 256 + threadIdx.x;
    if (i < BH_) {
        h0s[i]  = h0in[i];
        h1s[i]  = h0in[BH_ + i];
        c0s[i]  = c0in[i];
        c1s[i]  = c0in[BH_ + i];
        feed[i] = 0.0f;
    }
}

// ---------------------------------------------------------------------------
// pmem[r][k] = sum_j mem[r][j] * w_in[j][k]   (r = b*S+s; time-invariant)
// grid (128, 16), block 256.  64x64 tile, K-chunk 32, 4x4 outputs/thread.
// ---------------------------------------------------------------------------
__global__ __launch_bounds__(256) void k_pmem(
    const float* __restrict__ mem, const float* __restrict__ w_in,
    float* __restrict__ pmem)
{
    __shared__ float As[64][36];   // [row][k]  +pad
    __shared__ float Bs[32][68];   // [k][col]  +pad

    const int tid = threadIdx.x;
    const int rt = blockIdx.x * 64;
    const int ct = blockIdx.y * 64;
    const int tx = tid & 15;       // col group
    const int ty = tid >> 4;       // row group

    float acc[4][4] = {{0.f}};

    for (int jc = 0; jc < 1024; jc += 32) {
        #pragma unroll
        for (int i = 0; i < 2; ++i) {
            int s2  = tid + i * 256;            // 0..511
            int row = s2 >> 3, kq = s2 & 7;
            *(float4*)&As[row][kq * 4] =
                *(const float4*)(mem + (size_t)(rt + row) * 1024 + jc + kq * 4);
        }
        #pragma unroll
        for (int i = 0; i < 2; ++i) {
            int s2 = tid + i * 256;
            int kk = s2 >> 4, cq = s2 & 15;
            *(float4*)&Bs[kk][cq * 4] =
                *(const float4*)(w_in + (size_t)(jc + kk) * 1024 + ct + cq * 4);
        }
        __syncthreads();

        #pragma unroll
        for (int kk = 0; kk < 32; ++kk) {
            float a0 = As[ty * 4 + 0][kk], a1 = As[ty * 4 + 1][kk];
            float a2 = As[ty * 4 + 2][kk], a3 = As[ty * 4 + 3][kk];
            float b0 = Bs[kk][tx * 4 + 0], b1 = Bs[kk][tx * 4 + 1];
            float b2 = Bs[kk][tx * 4 + 2], b3 = Bs[kk][tx * 4 + 3];
            acc[0][0] += a0 * b0; acc[0][1] += a0 * b1; acc[0][2] += a0 * b2; acc[0][3] += a0 * b3;
            acc[1][0] += a1 * b0; acc[1][1] += a1 * b1; acc[1][2] += a1 * b2; acc[1][3] += a1 * b3;
            acc[2][0] += a2 * b0; acc[2][1] += a2 * b1; acc[2][2] += a2 * b2; acc[2][3] += a2 * b3;
            acc[3][0] += a3 * b0; acc[3][1] += a3 * b1; acc[3][2] += a3 * b2; acc[3][3] += a3 * b3;
        }
        __syncthreads();
    }

    #pragma unroll
    for (int i = 0; i < 4; ++i) {
        float4 v = make_float4(acc[i][0], acc[i][1], acc[i][2], acc[i][3]);
        *(float4*)(pmem + (size_t)(rt + ty * 4 + i) * 1024 + ct + tx * 4) = v;
    }
}

// ===========================================================================
// Round-2 GEMM bodies (proven): grid 512, block 256 = 32 b x 2 jl x 4 ks.
// ===========================================================================

// -------- LSTM layer 0: K = 2560 = [emb 512 | feed 1024 | h0 1024] ---------
__global__ __launch_bounds__(256) void k_lstm0(
    const int* __restrict__ tgt, const float* __restrict__ emb,
    const float* __restrict__ w_ih0, const float* __restrict__ w_hh0,
    const float* __restrict__ b_ih0, const float* __restrict__ b_hh0,
    const float* __restrict__ feed, const float* __restrict__ h0c,
    const float* __restrict__ c0c,
    float* __restrict__ h0n, float* __restrict__ c0n, int t)
{
    __shared__ float As[4][32][68];
    __shared__ float red[3][64][4];
    __shared__ int   tok[32];

    int tid = threadIdx.x;
    int b  = tid & 31;
    int jl = (tid >> 5) & 1;
    int ks = tid >> 6;
    int j  = blockIdx.x * 2 + jl;

    if (tid < 32) tok[tid] = tgt[tid * T_ + t];
    __syncthreads();

    float acc0, acc1, acc2, acc3;
    if (ks == 0) {
        acc0 = b_ih0[0 * H_ + j] + b_hh0[0 * H_ + j];
        acc1 = b_ih0[1 * H_ + j] + b_hh0[1 * H_ + j];
        acc2 = b_ih0[2 * H_ + j] + b_hh0[2 * H_ + j];
        acc3 = b_ih0[3 * H_ + j] + b_hh0[3 * H_ + j];
    } else {
        acc0 = acc1 = acc2 = acc3 = 0.0f;
    }

    for (int c = 0; c < 10; ++c) {
        #pragma unroll
        for (int i = 0; i < 8; ++i) {
            int q   = tid + i * 256;
            int ksq = q >> 9;
            int rem = q & 511;
            int bb  = rem >> 4;
            int kq  = rem & 15;
            int kg  = ksq * 640 + c * 64 + kq * 4;
            const float* src;
            if (kg < 512)        src = emb  + (size_t)tok[bb] * E_ + kg;
            else if (kg < 1536)  src = feed + (size_t)bb * H_ + (kg - 512);
            else                 src = h0c  + (size_t)bb * H_ + (kg - 1536);
            *(float4*)&As[ksq][bb][kq * 4] = *(const float4*)src;
        }
        __syncthreads();

        int kbase = ks * 640 + c * 64;
        const float4 *w0, *w1, *w2, *w3;
        if (kbase < 1536) {
            w0 = (const float4*)(w_ih0 + (size_t)(0 * H_ + j) * 1536 + kbase);
            w1 = (const float4*)(w_ih0 + (size_t)(1 * H_ + j) * 1536 + kbase);
            w2 = (const float4*)(w_ih0 + (size_t)(2 * H_ + j) * 1536 + kbase);
            w3 = (const float4*)(w_ih0 + (size_t)(3 * H_ + j) * 1536 + kbase);
        } else {
            int kb = kbase - 1536;
            w0 = (const float4*)(w_hh0 + (size_t)(0 * H_ + j) * 1024 + kb);
            w1 = (const float4*)(w_hh0 + (size_t)(1 * H_ + j) * 1024 + kb);
            w2 = (const float4*)(w_hh0 + (size_t)(2 * H_ + j) * 1024 + kb);
            w3 = (const float4*)(w_hh0 + (size_t)(3 * H_ + j) * 1024 + kb);
        }
        const float4* A4 = (const float4*)&As[ks][b][0];
        #pragma unroll
        for (int kk = 0; kk < 16; ++kk) {
            float4 a  = A4[kk];
            float4 q0 = w0[kk], q1 = w1[kk], q2 = w2[kk], q3 = w3[kk];
            acc0 += a.x * q0.x + a.y * q0.y + a.z * q0.z + a.w * q0.w;
            acc1 += a.x * q1.x + a.y * q1.y + a.z * q1.z + a.w * q1.w;
            acc2 += a.x * q2.x + a.y * q2.y + a.z * q2.z + a.w * q2.w;
            acc3 += a.x * q3.x + a.y * q3.y + a.z * q3.z + a.w * q3.w;
        }
        __syncthreads();
    }

    int idx = tid & 63;
    if (ks > 0) {
        red[ks - 1][idx][0] = acc0; red[ks - 1][idx][1] = acc1;
        red[ks - 1][idx][2] = acc2; red[ks - 1][idx][3] = acc3;
    }
    __syncthreads();
    if (ks == 0) {
        #pragma unroll
        for (int r = 0; r < 3; ++r) {
            acc0 += red[r][idx][0]; acc1 += red[r][idx][1];
            acc2 += red[r][idx][2]; acc3 += red[r][idx][3];
        }
        float co = c0c[b * H_ + j];
        float cn = sigm(acc1) * co + sigm(acc0) * tanh_(acc2);
        float hn = sigm(acc3) * tanh_(cn);
        c0n[b * H_ + j] = cn;
        h0n[b * H_ + j] = hn;
    }
}

// -------- LSTM layer 1: K = 2048 = [h0n 1024 | h1 1024] --------------------
__global__ __launch_bounds__(256) void k_lstm1(
    const float* __restrict__ w_ih1, const float* __restrict__ w_hh1,
    const float* __restrict__ b_ih1, const float* __restrict__ b_hh1,
    const float* __restrict__ x, const float* __restrict__ h1c,
    const float* __restrict__ c1c,
    float* __restrict__ h1n, float* __restrict__ c1n)
{
    __shared__ float As[4][32][68];
    __shared__ float red[3][64][4];

    int tid = threadIdx.x;
    int b  = tid & 31;
    int jl = (tid >> 5) & 1;
    int ks = tid >> 6;
    int j  = blockIdx.x * 2 + jl;

    float acc0, acc1, acc2, acc3;
    if (ks == 0) {
        acc0 = b_ih1[0 * H_ + j] + b_hh1[0 * H_ + j];
        acc1 = b_ih1[1 * H_ + j] + b_hh1[1 * H_ + j];
        acc2 = b_ih1[2 * H_ + j] + b_hh1[2 * H_ + j];
        acc3 = b_ih1[3 * H_ + j] + b_hh1[3 * H_ + j];
    } else {
        acc0 = acc1 = acc2 = acc3 = 0.0f;
    }

    for (int c = 0; c < 8; ++c) {
        #pragma unroll
        for (int i = 0; i < 8; ++i) {
            int q   = tid + i * 256;
            int ksq = q >> 9;
            int rem = q & 511;
            int bb  = rem >> 4;
            int kq  = rem & 15;
            int kg  = ksq * 512 + c * 64 + kq * 4;
            const float* src = (kg < 1024) ? (x + (size_t)bb * H_ + kg)
                                           : (h1c + (size_t)bb * H_ + (kg - 1024));
            *(float4*)&As[ksq][bb][kq * 4] = *(const float4*)src;
        }
        __syncthreads();

        int kbase = ks * 512 + c * 64;
        const float* wb;
        int ko;
        if (kbase < 1024) { wb = w_ih1; ko = kbase; }
        else              { wb = w_hh1; ko = kbase - 1024; }
        const float4* w0 = (const float4*)(wb + (size_t)(0 * H_ + j) * H_ + ko);
        const float4* w1 = (const float4*)(wb + (size_t)(1 * H_ + j) * H_ + ko);
        const float4* w2 = (const float4*)(wb + (size_t)(2 * H_ + j) * H_ + ko);
        const float4* w3 = (const float4*)(wb + (size_t)(3 * H_ + j) * H_ + ko);
        const float4* A4 = (const float4*)&As[ks][b][0];
        #pragma unroll
        for (int kk = 0; kk < 16; ++kk) {
            float4 a  = A4[kk];
            float4 q0 = w0[kk], q1 = w1[kk], q2 = w2[kk], q3 = w3[kk];
            acc0 += a.x * q0.x + a.y * q0.y + a.z * q0.z + a.w * q0.w;
            acc1 += a.x * q1.x + a.y * q1.y + a.z * q1.z + a.w * q1.w;
            acc2 += a.x * q2.x + a.y * q2.y + a.z * q2.z + a.w * q2.w;
            acc3 += a.x * q3.x + a.y * q3.y + a.z * q3.z + a.w * q3.w;
        }
        __syncthreads();
    }

    int idx = tid & 63;
    if (ks > 0) {
        red[ks - 1][idx][0] = acc0; red[ks - 1][idx][1] = acc1;
        red[ks - 1][idx][2] = acc2; red[ks - 1][idx][3] = acc3;
    }
    __syncthreads();
    if (ks == 0) {
        #pragma unroll
        for (int r = 0; r < 3; ++r) {
            acc0 += red[r][idx][0]; acc1 += red[r][idx][1];
            acc2 += red[r][idx][2]; acc3 += red[r][idx][3];
        }
        float co = c1c[b * H_ + j];
        float cn = sigm(acc1) * co + sigm(acc0) * tanh_(acc2);
        float hn = sigm(acc3) * tanh_(cn);
        c1n[b * H_ + j] = cn;
        h1n[b * H_ + j] = hn;
    }
}

// -------- q = h1n @ w_in^T (FALLBACK PATH ONLY) ----------------------------
__global__ __launch_bounds__(256) void k_q(
    const float* __restrict__ w_in, const float* __restrict__ h1n,
    float* __restrict__ q_out)
{
    __shared__ float As[4][32][68];
    __shared__ float red[3][64];

    int tid = threadIdx.x;
    int b  = tid & 31;
    int jl = (tid >> 5) & 1;
    int ks = tid >> 6;
    int j  = blockIdx.x * 2 + jl;

    float acc = 0.0f;
    for (int c = 0; c < 4; ++c) {
        #pragma unroll
        for (int i = 0; i < 8; ++i) {
            int q   = tid + i * 256;
            int ksq = q >> 9;
            int rem = q & 511;
            int bb  = rem >> 4;
            int kq  = rem & 15;
            int kg  = ksq * 256 + c * 64 + kq * 4;
            *(float4*)&As[ksq][bb][kq * 4] = *(const float4*)(h1n + (size_t)bb * H_ + kg);
        }
        __syncthreads();

        int kbase = ks * 256 + c * 64;
        const float4* w0 = (const float4*)(w_in + (size_t)j * H_ + kbase);
        const float4* A4 = (const float4*)&As[ks][b][0];
        #pragma unroll
        for (int kk = 0; kk < 16; ++kk) {
            float4 a  = A4[kk];
            float4 q0 = w0[kk];
            acc += a.x * q0.x + a.y * q0.y + a.z * q0.z + a.w * q0.w;
        }
        __syncthreads();
    }

    int idx = tid & 63;
    if (ks > 0) red[ks - 1][idx] = acc;
    __syncthreads();
    if (ks == 0) {
        acc += red[0][idx] + red[1][idx] + red[2][idx];
        q_out[b * H_ + j] = acc;
    }
}

// ---------------------------------------------------------------------------
// scores[b][s] = x[b] . base[b][s]   grid 512 = b(32) x stile(16), block 256.
// ---------------------------------------------------------------------------
__global__ __launch_bounds__(256) void k_scores(
    const float* __restrict__ x_in, const float* __restrict__ base,
    float* __restrict__ sc_out)
{
    __shared__ float q_lds[1024];

    int b  = blockIdx.x >> 4;
    int st = blockIdx.x & 15;
    int tid  = threadIdx.x;
    int lane = tid & 63;
    int wv   = tid >> 6;

    ((float4*)q_lds)[tid] = ((const float4*)(x_in + (size_t)b * H_))[tid];
    __syncthreads();

    float4 q4[4];
    #pragma unroll
    for (int i = 0; i < 4; ++i) q4[i] = ((const float4*)q_lds)[lane + 64 * i];

    const float* mb = base + (size_t)b * S_ * H_;
    #pragma unroll
    for (int ss = 0; ss < 4; ++ss) {
        int s = st * 16 + wv * 4 + ss;
        const float4* mr = (const float4*)(mb + (size_t)s * H_);
        float a = 0.0f;
        #pragma unroll
        for (int i = 0; i < 4; ++i) {
            float4 m = mr[lane + 64 * i];
            a += q4[i].x * m.x + q4[i].y * m.y + q4[i].z * m.z + q4[i].w * m.w;
        }
        #pragma unroll
        for (int o = 32; o > 0; o >>= 1) a += __shfl_down(a, o);
        if (lane == 0) sc_out[b * S_ + s] = a;
    }
}

// ---------------------------------------------------------------------------
// ctx: local masked softmax of scores + weighted sum.  grid 512, block 256
// ---------------------------------------------------------------------------
__global__ __launch_bounds__(256) void k_ctx(
    const float* __restrict__ sc_in, const float* __restrict__ mem,
    const int* __restrict__ masks,
    float* __restrict__ ctx, float* __restrict__ attn_out, int t)
{
    __shared__ float aw[256];
    __shared__ float red2[4][64];

    int b  = blockIdx.x >> 4;
    int ht = blockIdx.x & 15;
    int tid  = threadIdx.x;
    int lane = tid & 63;
    int wv   = tid >> 6;

    if (wv == 0) {
        int m = 0;
        #pragma unroll
        for (int i = 0; i < 4; ++i) m += masks[b * S_ + lane * 4 + i];
        #pragma unroll
        for (int o = 32; o > 0; o >>= 1) m += __shfl_down(m, o);
        int len = __shfl(m, 0);

        float v[4];
        float mx = -1e30f;
        #pragma unroll
        for (int i = 0; i < 4; ++i) {
            int s = lane + 64 * i;
            float xv = (s < len) ? sc_in[b * S_ + s] : -1e9f;
            v[i] = xv;
            mx = fmaxf(mx, xv);
        }
        #pragma unroll
        for (int o = 32; o > 0; o >>= 1) mx = fmaxf(mx, __shfl_xor(mx, o));
        float sm = 0.0f;
        #pragma unroll
        for (int i = 0; i < 4; ++i) { v[i] = __expf(v[i] - mx); sm += v[i]; }
        #pragma unroll
        for (int o = 32; o > 0; o >>= 1) sm += __shfl_xor(sm, o);
        float inv = 1.0f / sm;
        #pragma unroll
        for (int i = 0; i < 4; ++i) {
            int s = lane + 64 * i;
            float w = v[i] * inv;
            aw[s] = w;
            if (ht == 0) attn_out[((size_t)b * T_ + t) * S_ + s] = w;
        }
    }
    __syncthreads();

    int h = ht * 64 + lane;
    const float* mb = mem + (size_t)b * S_ * H_;
    float a = 0.0f;
    #pragma unroll 8
    for (int ss = 0; ss < 64; ++ss) {
        int s = wv * 64 + ss;
        a += aw[s] * mb[(size_t)s * H_ + h];
    }
    red2[wv][lane] = a;
    __syncthreads();
    if (tid < 64) {
        float r = red2[0][tid] + red2[1][tid] + red2[2][tid] + red2[3][tid];
        ctx[b * H_ + ht * 64 + tid] = r;
    }
}

// -------- out = tanh([ctx | h1n] @ w_out^T) --------------------------------
__global__ __launch_bounds__(256) void k_out(
    const float* __restrict__ w_out, const float* __restrict__ ctx,
    const float* __restrict__ h1n,
    float* __restrict__ feedn, float* __restrict__ dout, int t)
{
    __shared__ float As[4][32][68];
    __shared__ float red[3][64];

    int tid = threadIdx.x;
    int b  = tid & 31;
    int jl = (tid >> 5) & 1;
    int ks = tid >> 6;
    int j  = blockIdx.x * 2 + jl;

    float acc = 0.0f;
    for (int c = 0; c < 8; ++c) {
        #pragma unroll
        for (int i = 0; i < 8; ++i) {
            int q   = tid + i * 256;
            int ksq = q >> 9;
            int rem = q & 511;
            int bb  = rem >> 4;
            int kq  = rem & 15;
            int kg  = ksq * 512 + c * 64 + kq * 4;
            const float* src = (kg < 1024) ? (ctx + (size_t)bb * H_ + kg)
                                           : (h1n + (size_t)bb * H_ + (kg - 1024));
            *(float4*)&As[ksq][bb][kq * 4] = *(const float4*)src;
        }
        __syncthreads();

        int kbase = ks * 512 + c * 64;
        const float4* w0 = (const float4*)(w_out + (size_t)j * 2048 + kbase);
        const float4* A4 = (const float4*)&As[ks][b][0];
        #pragma unroll
        for (int kk = 0; kk < 16; ++kk) {
            float4 a  = A4[kk];
            float4 q0 = w0[kk];
            acc += a.x * q0.x + a.y * q0.y + a.z * q0.z + a.w * q0.w;
        }
        __syncthreads();
    }

    int idx = tid & 63;
    if (ks > 0) red[ks - 1][idx] = acc;
    __syncthreads();
    if (ks == 0) {
        acc += red[0][idx] + red[1][idx] + red[2][idx];
        float o = tanh_(acc);
        feedn[b * H_ + j] = o;
        dout[((size_t)b * T_ + t) * H_ + j] = o;
    }
}

// ---------------------------------------------------------------------------
extern "C" void kernel_launch(void* const* d_in, const int* in_sizes, int n_in,
                              void* d_out, int out_size, void* d_ws, size_t ws_size,
                              hipStream_t stream) {
    const int*   tgt    = (const int*)  d_in[0];
    const float* mem    = (const float*)d_in[1];
    const int*   masks  = (const int*)  d_in[2];
    const float* h0in   = (const float*)d_in[3];
    const float* c0in   = (const float*)d_in[4];
    const float* emb    = (const float*)d_in[5];
    const float* w_ih0  = (const float*)d_in[6];
    const float* w_hh0  = (const float*)d_in[7];
    const float* b_ih0  = (const float*)d_in[8];
    const float* b_hh0  = (const float*)d_in[9];
    const float* w_ih1  = (const float*)d_in[10];
    const float* w_hh1  = (const float*)d_in[11];
    const float* b_ih1  = (const float*)d_in[12];
    const float* b_hh1  = (const float*)d_in[13];
    const float* w_in   = (const float*)d_in[14];
    const float* w_out  = (const float*)d_in[15];

    float* dout     = (float*)d_out;
    float* attn_out = dout + (size_t)B_ * T_ * H_;

    float* ws   = (float*)d_ws;
    float* h0s  = ws;              // [2][B*H]
    float* c0s  = h0s  + 2 * BH_;  // [2][B*H]
    float* h1s  = c0s  + 2 * BH_;  // [2][B*H]
    float* c1s  = h1s  + 2 * BH_;  // [2][B*H]
    float* feed = c1s  + 2 * BH_;  // [2][B*H]
    float* qctx = feed + 2 * BH_;  // [B*H]   (ctx; fallback also uses as q)
    float* scw  = qctx + BH_;      // [B*S]
    float* pmem = scw  + B_ * S_;  // [B*S*H] = 33.5 MB

    const size_t need = ((size_t)(11 * BH_ + B_ * S_) + (size_t)B_ * S_ * H_) * 4;
    const bool use_pmem = (ws_size >= need);

    k_init<<<128, 256, 0, stream>>>(h0in, c0in, h0s, c0s, h1s, c1s, feed);

    if (use_pmem) {
        k_pmem<<<dim3(128, 16), 256, 0, stream>>>(mem, w_in, pmem);

        for (int t = 0; t < T_; ++t) {
            int cur = t & 1, nxt = cur ^ 1;
            k_lstm0<<<512, 256, 0, stream>>>(tgt, emb, w_ih0, w_hh0, b_ih0, b_hh0,
                                             feed + cur * BH_, h0s + cur * BH_, c0s + cur * BH_,
                                             h0s + nxt * BH_, c0s + nxt * BH_, t);
            k_nop<<<1, 64, 0, stream>>>();           // gap probe #1
            k_lstm1<<<512, 256, 0, stream>>>(w_ih1, w_hh1, b_ih1, b_hh1,
                                             h0s + nxt * BH_, h1s + cur * BH_, c1s + cur * BH_,
                                             h1s + nxt * BH_, c1s + nxt * BH_);
            k_scores<<<512, 256, 0, stream>>>(h1s + nxt * BH_, pmem, scw);
            k_nop<<<1, 64, 0, stream>>>();           // gap probe #2
            k_ctx<<<512, 256, 0, stream>>>(scw, mem, masks, qctx, attn_out, t);
            k_out<<<512, 256, 0, stream>>>(w_out, qctx, h1s + nxt * BH_,
                                           feed + nxt * BH_, dout, t);
        }
    } else {
        for (int t = 0; t < T_; ++t) {
            int cur = t & 1, nxt = cur ^ 1;
            k_lstm0<<<512, 256, 0, stream>>>(tgt, emb, w_ih0, w_hh0, b_ih0, b_hh0,
                                             feed + cur * BH_, h0s + cur * BH_, c0s + cur * BH_,
                                             h0s + nxt * BH_, c0s + nxt * BH_, t);
            k_lstm1<<<512, 256, 0, stream>>>(w_ih1, w_hh1, b_ih1, b_hh1,
                                             h0s + nxt * BH_, h1s + cur * BH_, c1s + cur * BH_,
                                             h1s + nxt * BH_, c1s + nxt * BH_);
            k_q<<<512, 256, 0, stream>>>(w_in, h1s + nxt * BH_, qctx);
            k_scores<<<512, 256, 0, stream>>>(qctx, mem, scw);
            k_ctx<<<512, 256, 0, stream>>>(scw, mem, masks, qctx, attn_out, t);
            k_out<<<512, 256, 0, stream>>>(w_out, qctx, h1s + nxt * BH_,
                                           feed + nxt * BH_, dout, t);
        }
    }
}